// Round 10
// baseline (223.346 us; speedup 1.0000x reference)
//
#include <hip/hip_runtime.h>
#include <hip/hip_bf16.h>

// Problem constants (from reference): B=8, T=4096, E=16, H=64
#define BB 8
#define TT 4096
#define EE 16
#define HH 64
#define ZT 16      // colsum t-chunk split (grid 2048 = 8 blocks/CU)

typedef __attribute__((ext_vector_type(8))) __bf16 bf16x8;  // MFMA A/B frag (4 VGPRs)
typedef __attribute__((ext_vector_type(4))) __bf16 bf16x4;  // packed E write (8B)
typedef __attribute__((ext_vector_type(4))) float f32x4;    // MFMA C/D frag

typedef __attribute__((address_space(3))) void lds_void;
typedef const __attribute__((address_space(1))) void gl_void;

// e^(d^(-1/16)) ≈ P4(log2(d) - 5.5): degree-4 Taylor of exp(2^(-u/16)) about
// u=5.5. |rel err| < 2.5e-4 for d ∈ [2,1024] — inside bf16 noise (validated
// R6-R9: absmax identical to 3-transcendental version). 1 transc + 5 VALU.
static __device__ __forceinline__ float exp_pow16(float d) {
    float t = __builtin_amdgcn_logf(d) - 5.5f;     // v_log_f32 = log2
    float r = __builtin_fmaf(t, 2.72889e-6f, -9.35716e-5f);
    r = __builtin_fmaf(t, r, 2.90736e-3f);
    r = __builtin_fmaf(t, r, -7.50656e-2f);
    r = __builtin_fmaf(t, r, 2.198967f);
    return r;
}

// ---- kernel 1: Qb = bf16(x@Wq), Kb = bf16(x@Wk) ----------------------------
__global__ __launch_bounds__(256) void proj_kernel(
        const float* __restrict__ x, const float* __restrict__ Wq,
        const float* __restrict__ Wk,
        __bf16* __restrict__ Qb, __bf16* __restrict__ Kb) {
    int tid = threadIdx.x;
    int row = blockIdx.x * 4 + (tid >> 6);
    int h = tid & 63;
    const float* xr = x + (size_t)row * EE;
    float q = 0.f, k = 0.f;
#pragma unroll
    for (int e = 0; e < EE; ++e) {
        float xv = xr[e];
        q += xv * Wq[e * HH + h];
        k += xv * Wk[e * HH + h];
    }
    size_t idx = (size_t)row * HH + h;
    Qb[idx] = (__bf16)q;
    Kb[idx] = (__bf16)k;
}

// ---- kernel 2: Dpart[z][b][s] = sum_{t in chunk z} exp((q_t.k_s)^(-1/16)) --
// R10: ring-3 staged-Q pipeline, ONE s_barrier per iter. Per iter i:
//   vmcnt(1)  -> my chunk-i load (issued at iter i-2) complete
//   s_barrier -> everyone's chunk-i staged; buf[(i+2)%3] consumed by all in
//                iter i-1 (data delivered pre-barrier) -> safe to overwrite
//   stage chunk i+2; consume buf[i%3].
__global__ __launch_bounds__(256, 4) void colsum_mfma(
        const __bf16* __restrict__ Qb, const __bf16* __restrict__ Kb,
        float* __restrict__ Dpart) {
    __shared__ __bf16 QKf[3][4][64][8];   // [buf][region tsub*2+kh][lane][8]

    int lane = threadIdx.x & 63;
    int w = threadIdx.x >> 6;
    int quad = lane >> 4;
    int l15 = lane & 15;
    int b = blockIdx.y;
    int z = blockIdx.z;
    int s0 = blockIdx.x * 256 + w * 64;

    const __bf16* Qbb = Qb + (size_t)b * TT * HH;
    const __bf16* Kbb = Kb + (size_t)b * TT * HH;

    bf16x8 bk[4][2];
#pragma unroll
    for (int st = 0; st < 4; ++st) {
        const __bf16* krow = Kbb + (size_t)(s0 + st * 16 + l15) * HH + quad * 8;
        bk[st][0] = *(const bf16x8*)(krow);
        bk[st][1] = *(const bf16x8*)(krow + 32);
    }

    const __bf16* gA = Qbb + (size_t)((w >> 1) * 16 + l15) * HH + quad * 8 + (w & 1) * 32;

    const int TL = TT / ZT;                  // 256 t per block
    int t0 = z * TL;
    const int niter = TL / 32;               // 8

    // Prologue: stage chunks 0,1 into bufs 0,1.
    __builtin_amdgcn_global_load_lds((gl_void*)(gA + (size_t)t0 * HH),
                                     (lds_void*)&QKf[0][w][0][0], 16, 0, 0);
    __builtin_amdgcn_global_load_lds((gl_void*)(gA + (size_t)(t0 + 32) * HH),
                                     (lds_void*)&QKf[1][w][0][0], 16, 0, 0);

    float csum[4] = {0.f, 0.f, 0.f, 0.f};
    int bufi = 0;
    for (int i = 0; i < niter; ++i) {
        __builtin_amdgcn_s_waitcnt(0x0f71);   // vmcnt(1): chunk-i stage done
        __builtin_amdgcn_s_barrier();
        int tn = (i + 2 < niter) ? (t0 + (i + 2) * 32) : t0;   // dummy at tail
        int sb = bufi + 2; if (sb >= 3) sb -= 3;
        __builtin_amdgcn_global_load_lds((gl_void*)(gA + (size_t)tn * HH),
                                         (lds_void*)&QKf[sb][w][0][0], 16, 0, 0);

        bf16x8 aq[2][2];
#pragma unroll
        for (int tsub = 0; tsub < 2; ++tsub)
#pragma unroll
            for (int kh = 0; kh < 2; ++kh)
                aq[tsub][kh] = *(const bf16x8*)&QKf[bufi][tsub * 2 + kh][lane][0];

#pragma unroll
        for (int st = 0; st < 4; ++st) {
            f32x4 c0 = {0.f, 0.f, 0.f, 0.f};
            f32x4 c1 = {0.f, 0.f, 0.f, 0.f};
            c0 = __builtin_amdgcn_mfma_f32_16x16x32_bf16(aq[0][0], bk[st][0], c0, 0, 0, 0);
            c1 = __builtin_amdgcn_mfma_f32_16x16x32_bf16(aq[1][0], bk[st][0], c1, 0, 0, 0);
            c0 = __builtin_amdgcn_mfma_f32_16x16x32_bf16(aq[0][1], bk[st][1], c0, 0, 0, 0);
            c1 = __builtin_amdgcn_mfma_f32_16x16x32_bf16(aq[1][1], bk[st][1], c1, 0, 0, 0);
            csum[st] += exp_pow16(c0[0]) + exp_pow16(c0[1])
                      + exp_pow16(c0[2]) + exp_pow16(c0[3])
                      + exp_pow16(c1[0]) + exp_pow16(c1[1])
                      + exp_pow16(c1[2]) + exp_pow16(c1[3]);
        }
        bufi = bufi + 1; if (bufi >= 3) bufi = 0;
    }

#pragma unroll
    for (int st = 0; st < 4; ++st) {
        float r = csum[st];
        r += __shfl_xor(r, 16, 64);           // sum across quads (t-rows)
        r += __shfl_xor(r, 32, 64);
        if (quad == 0)
            Dpart[((size_t)z * BB + b) * TT + s0 + st * 16 + l15] = r;
    }
}

// ---- kernel 3: VsT[b][h][s] = bf16(Kb[b][s][h]) / sum_z Dpart[z][b][s] -----
__global__ __launch_bounds__(256) void vscale_kernel(
        const __bf16* __restrict__ Kb, const float* __restrict__ Dpart,
        __bf16* __restrict__ VsT) {
    __shared__ float tile[64][65];
    __shared__ float Rs[64];                  // 1/D per s_local
    int b = blockIdx.y;
    int s0 = blockIdx.x * 64;
    int c = threadIdx.x & 63;
    int rr = threadIdx.x >> 6;
    if (threadIdx.x < 64) {
        size_t si = (size_t)b * TT + s0 + threadIdx.x;
        float d = Dpart[si];
#pragma unroll
        for (int zz = 1; zz < ZT; ++zz) d += Dpart[(size_t)zz * BB * TT + si];
        Rs[threadIdx.x] = 1.0f / d;
    }
    __syncthreads();
    const __bf16* Kbase = Kb + ((size_t)b * TT + s0) * HH;
#pragma unroll
    for (int i = rr; i < 64; i += 4)
        tile[i][c] = (float)Kbase[(size_t)i * HH + c] * Rs[i];   // tile[s_local][h]
    __syncthreads();
    __bf16* Vb = VsT + (size_t)b * HH * TT;
#pragma unroll
    for (int i = rr; i < 64; i += 4)
        Vb[(size_t)i * TT + s0 + c] = (__bf16)tile[c][i];        // VsT[h=i][s=s0+c]
}

// ---- kernel 4: OP[z][b][t][h] = sum_{s in slice z} exp(S_ts) * VsT[h][s] ---
// R10: ring-3 staging, ONE barrier per iter (same protocol as colsum; 2 loads
// per wave per iter -> vmcnt(2)). R8's S^T operand swap + packed b64 E writes.
__global__ __launch_bounds__(256, 4) void out_mfma(
        const __bf16* __restrict__ Qb, const __bf16* __restrict__ Kb,
        const __bf16* __restrict__ VsT, float* __restrict__ OP) {
    __shared__ __bf16 QKf[3][4][64][8];     // [buf][region sub*2+kh][lane][8]
    __shared__ __bf16 PVf[3][4][64][8];     // [buf][region ht][lane][8]
    __shared__ __bf16 Etile[4][2][16 * 40]; // per-wave, per-tile E[t 16][s 32+pad8]

    int lane = threadIdx.x & 63;
    int w = threadIdx.x >> 6;
    int quad = lane >> 4;
    int l15 = lane & 15;
    int b = blockIdx.y;
    int z = blockIdx.z;
    int t0 = blockIdx.x * 128 + w * 32;

    const __bf16* Qbb = Qb + (size_t)b * TT * HH;
    const __bf16* Kbb = Kb + (size_t)b * TT * HH;
    const __bf16* Vbb = VsT + (size_t)b * HH * TT;

    bf16x8 aq[2][2];
#pragma unroll
    for (int tile = 0; tile < 2; ++tile) {
        const __bf16* qrow = Qbb + (size_t)(t0 + tile * 16 + l15) * HH + quad * 8;
        aq[tile][0] = *(const bf16x8*)(qrow);
        aq[tile][1] = *(const bf16x8*)(qrow + 32);
    }

    f32x4 acc[2][4];
#pragma unroll
    for (int tile = 0; tile < 2; ++tile)
#pragma unroll
        for (int ht = 0; ht < 4; ++ht)
            acc[tile][ht] = (f32x4){0.f, 0.f, 0.f, 0.f};

    const __bf16* gA = Kbb + (size_t)((w >> 1) * 16 + l15) * HH + quad * 8 + (w & 1) * 32;
    const __bf16* gB = Vbb + (size_t)(w * 16 + l15) * TT + quad * 8;

    const int SL = TT / gridDim.z;
    int s0z = z * SL;
    const int niter = SL / 32;

    // Prologue: stage chunks 0,1 into bufs 0,1.
    __builtin_amdgcn_global_load_lds((gl_void*)(gA + (size_t)s0z * HH),
                                     (lds_void*)&QKf[0][w][0][0], 16, 0, 0);
    __builtin_amdgcn_global_load_lds((gl_void*)(gB + s0z),
                                     (lds_void*)&PVf[0][w][0][0], 16, 0, 0);
    __builtin_amdgcn_global_load_lds((gl_void*)(gA + (size_t)(s0z + 32) * HH),
                                     (lds_void*)&QKf[1][w][0][0], 16, 0, 0);
    __builtin_amdgcn_global_load_lds((gl_void*)(gB + s0z + 32),
                                     (lds_void*)&PVf[1][w][0][0], 16, 0, 0);

    int bufi = 0;
    for (int i = 0; i < niter; ++i) {
        __builtin_amdgcn_s_waitcnt(0x0f72);   // vmcnt(2): chunk-i stages done
        __builtin_amdgcn_s_barrier();
        int sn = (i + 2 < niter) ? (s0z + (i + 2) * 32) : s0z;   // dummy at tail
        int sb = bufi + 2; if (sb >= 3) sb -= 3;
        __builtin_amdgcn_global_load_lds((gl_void*)(gA + (size_t)sn * HH),
                                         (lds_void*)&QKf[sb][w][0][0], 16, 0, 0);
        __builtin_amdgcn_global_load_lds((gl_void*)(gB + sn),
                                         (lds_void*)&PVf[sb][w][0][0], 16, 0, 0);

        bf16x8 bk[2][2], bv[4];
#pragma unroll
        for (int sub = 0; sub < 2; ++sub)
#pragma unroll
            for (int kh = 0; kh < 2; ++kh)
                bk[sub][kh] = *(const bf16x8*)&QKf[bufi][sub * 2 + kh][lane][0];
#pragma unroll
        for (int ht = 0; ht < 4; ++ht)
            bv[ht] = *(const bf16x8*)&PVf[bufi][ht][lane][0];

#pragma unroll
        for (int tile = 0; tile < 2; ++tile) {
#pragma unroll
            for (int sub = 0; sub < 2; ++sub) {
                // S^T: A=K (m=s), B=Q (n=t) -> row = s_local = quad*4+r,
                // col = t_local = l15. 4 regs = 4 consecutive s.
                f32x4 c = {0.f, 0.f, 0.f, 0.f};
                c = __builtin_amdgcn_mfma_f32_16x16x32_bf16(bk[sub][0], aq[tile][0], c, 0, 0, 0);
                c = __builtin_amdgcn_mfma_f32_16x16x32_bf16(bk[sub][1], aq[tile][1], c, 0, 0, 0);
                bf16x4 e;
#pragma unroll
                for (int r = 0; r < 4; ++r)
                    e[r] = (__bf16)exp_pow16(c[r]);
                // E[t=l15][s = sub*16 + quad*4 .. +3]: one packed 8B write
                *(bf16x4*)&Etile[w][tile][l15 * 40 + sub * 16 + quad * 4] = e;
            }
        }
        __builtin_amdgcn_s_waitcnt(0xc07f);   // lgkmcnt(0): E writes visible
#pragma unroll
        for (int tile = 0; tile < 2; ++tile) {
            // A-frag from E: A[m=t=l15][k=s=quad*8+j] — contiguous b128
            bf16x8 aE = *(const bf16x8*)&Etile[w][tile][l15 * 40 + quad * 8];
#pragma unroll
            for (int ht = 0; ht < 4; ++ht)
                acc[tile][ht] = __builtin_amdgcn_mfma_f32_16x16x32_bf16(aE, bv[ht], acc[tile][ht], 0, 0, 0);
        }
        bufi = bufi + 1; if (bufi >= 3) bufi = 0;
    }

    float* op = OP + (((size_t)z * BB + b) * TT + t0) * HH;
#pragma unroll
    for (int tile = 0; tile < 2; ++tile) {
#pragma unroll
        for (int r = 0; r < 4; ++r) {
            size_t ro = (size_t)(tile * 16 + quad * 4 + r) * HH + l15;
            op[ro]      = acc[tile][0][r];
            op[ro + 16] = acc[tile][1][r];
            op[ro + 32] = acc[tile][2][r];
            op[ro + 48] = acc[tile][3][r];
        }
    }
}

// ---- kernel 5: out = sum_z OP[z] -------------------------------------------
__global__ __launch_bounds__(256) void reduce_kernel(
        const float* __restrict__ OP, float* __restrict__ out, int nslice) {
    size_t i = (size_t)blockIdx.x * 256 + threadIdx.x;   // float4 units
    const size_t N4 = (size_t)BB * TT * HH / 4;
    if (i >= N4) return;
    const float4* p = (const float4*)OP;
    float4 a = p[i];
    for (int zz = 1; zz < nslice; ++zz) {
        float4 v = p[(size_t)zz * N4 + i];
        a.x += v.x; a.y += v.y; a.z += v.z; a.w += v.w;
    }
    ((float4*)out)[i] = a;
}

extern "C" void kernel_launch(void* const* d_in, const int* in_sizes, int n_in,
                              void* d_out, int out_size, void* d_ws, size_t ws_size,
                              hipStream_t stream) {
    const float* x  = (const float*)d_in[0];
    const float* Wq = (const float*)d_in[1];
    const float* Wk = (const float*)d_in[2];
    // d_in[3] (Wv) unused: reference computes v = x @ Wk (faithful quirk).

    const size_t NE = (size_t)BB * TT * HH;     // 2,097,152
    size_t base = NE * 2 * 3 + (size_t)ZT * BB * TT * 4;
    int nslice = 8;
    if (base + (size_t)8 * NE * 4 > ws_size) nslice = 4;
    if (base + (size_t)4 * NE * 4 > ws_size) nslice = 2;

    char* wp = (char*)d_ws;
    __bf16* Qb    = (__bf16*)wp;  wp += NE * 2;
    __bf16* Kb    = (__bf16*)wp;  wp += NE * 2;
    __bf16* VsT   = (__bf16*)wp;  wp += NE * 2;
    float*  Dpart = (float*)wp;   wp += (size_t)ZT * BB * TT * 4;
    float*  OP    = (float*)wp;
    float* out = (float*)d_out;

    proj_kernel<<<BB * TT / 4, 256, 0, stream>>>(x, Wq, Wk, Qb, Kb);
    colsum_mfma<<<dim3(TT / 256, BB, ZT), 256, 0, stream>>>(Qb, Kb, Dpart);
    vscale_kernel<<<dim3(TT / 64, BB), 256, 0, stream>>>(Kb, Dpart, VsT);
    out_mfma<<<dim3(TT / 128, BB, nslice), 256, 0, stream>>>(Qb, Kb, VsT, OP);
    reduce_kernel<<<(int)((NE / 4 + 255) / 256), 256, 0, stream>>>(OP, out, nslice);
}

// Round 11
// 174.647 us; speedup vs baseline: 1.2788x; 1.2788x over previous
//
#include <hip/hip_runtime.h>
#include <hip/hip_bf16.h>

// Problem constants (from reference): B=8, T=4096, E=16, H=64
#define BB 8
#define TT 4096
#define EE 16
#define HH 64
#define ZT 4       // colsum t-chunk split (R8 value — best known)

typedef __attribute__((ext_vector_type(8))) __bf16 bf16x8;  // K=32 MFMA A/B frag
typedef __attribute__((ext_vector_type(4))) __bf16 bf16x4;  // K=16 MFMA A/B frag
typedef __attribute__((ext_vector_type(4))) float f32x4;    // MFMA C/D frag
typedef __attribute__((ext_vector_type(4))) short short4v;

typedef __attribute__((address_space(3))) void lds_void;
typedef const __attribute__((address_space(1))) void gl_void;

// K=16 bf16 MFMA (v_mfma_f32_16x16x16_bf16, gfx950 ISA §10: A/B = 2 VGPRs).
// Builtin name differs across ROCm versions — select at compile time.
static __device__ __forceinline__ f32x4 mfma16_bf16(bf16x4 a, bf16x4 b, f32x4 c) {
#if __has_builtin(__builtin_amdgcn_mfma_f32_16x16x16_bf16)
    return __builtin_amdgcn_mfma_f32_16x16x16_bf16(a, b, c, 0, 0, 0);
#elif __has_builtin(__builtin_amdgcn_mfma_f32_16x16x16bf16_1k)
    return __builtin_amdgcn_mfma_f32_16x16x16bf16_1k(
        __builtin_bit_cast(short4v, a), __builtin_bit_cast(short4v, b), c, 0, 0, 0);
#else
    f32x4 d = c;
    asm volatile("v_mfma_f32_16x16x16_bf16 %0, %1, %2, %0"
                 : "+v"(d) : "v"(a), "v"(b));
    return d;
#endif
}

// e^(d^(-1/16)) ≈ P4(log2(d) - 5.5); |rel err| < 2.5e-4 for d ∈ [2,1024]
// (validated R6-R10: absmax identical to 3-transcendental version).
static __device__ __forceinline__ float exp_pow16(float d) {
    float t = __builtin_amdgcn_logf(d) - 5.5f;     // v_log_f32 = log2
    float r = __builtin_fmaf(t, 2.72889e-6f, -9.35716e-5f);
    r = __builtin_fmaf(t, r, 2.90736e-3f);
    r = __builtin_fmaf(t, r, -7.50656e-2f);
    r = __builtin_fmaf(t, r, 2.198967f);
    return r;
}

// ---- kernel 1: Qb = bf16(x@Wq), Kb = bf16(x@Wk) ----------------------------
__global__ __launch_bounds__(256) void proj_kernel(
        const float* __restrict__ x, const float* __restrict__ Wq,
        const float* __restrict__ Wk,
        __bf16* __restrict__ Qb, __bf16* __restrict__ Kb) {
    int tid = threadIdx.x;
    int row = blockIdx.x * 4 + (tid >> 6);
    int h = tid & 63;
    const float* xr = x + (size_t)row * EE;
    float q = 0.f, k = 0.f;
#pragma unroll
    for (int e = 0; e < EE; ++e) {
        float xv = xr[e];
        q += xv * Wq[e * HH + h];
        k += xv * Wk[e * HH + h];
    }
    size_t idx = (size_t)row * HH + h;
    Qb[idx] = (__bf16)q;
    Kb[idx] = (__bf16)k;
}

// ---- kernel 2: Dpart[z][b][s] (R8 structure verbatim — best known) ---------
__global__ __launch_bounds__(256, 4) void colsum_mfma(
        const __bf16* __restrict__ Qb, const __bf16* __restrict__ Kb,
        float* __restrict__ Dpart) {
    __shared__ __bf16 QKf[2][4][64][8];   // [buf][region tsub*2+kh][lane][8]

    int lane = threadIdx.x & 63;
    int w = threadIdx.x >> 6;
    int quad = lane >> 4;
    int l15 = lane & 15;
    int b = blockIdx.y;
    int z = blockIdx.z;
    int s0 = blockIdx.x * 256 + w * 64;

    const __bf16* Qbb = Qb + (size_t)b * TT * HH;
    const __bf16* Kbb = Kb + (size_t)b * TT * HH;

    bf16x8 bk[4][2];
#pragma unroll
    for (int st = 0; st < 4; ++st) {
        const __bf16* krow = Kbb + (size_t)(s0 + st * 16 + l15) * HH + quad * 8;
        bk[st][0] = *(const bf16x8*)(krow);
        bk[st][1] = *(const bf16x8*)(krow + 32);
    }

    const __bf16* gA = Qbb + (size_t)((w >> 1) * 16 + l15) * HH + quad * 8 + (w & 1) * 32;

    const int TL = TT / ZT;                  // 1024 t per block
    int t0 = z * TL, tend = t0 + TL;

    __builtin_amdgcn_global_load_lds((gl_void*)(gA + (size_t)t0 * HH),
                                     (lds_void*)&QKf[0][w][0][0], 16, 0, 0);

    float csum[4] = {0.f, 0.f, 0.f, 0.f};
    int buf = 0;
    for (int t = t0; t < tend; t += 32) {
        int tn = (t + 32 < tend) ? (t + 32) : t0;   // last iter: dummy reload
        int nb = buf ^ 1;
        __builtin_amdgcn_global_load_lds((gl_void*)(gA + (size_t)tn * HH),
                                         (lds_void*)&QKf[nb][w][0][0], 16, 0, 0);
        __builtin_amdgcn_s_waitcnt(0x0f71);   // vmcnt(1): chunk-t stage complete
        __builtin_amdgcn_s_barrier();

        bf16x8 aq[2][2];
#pragma unroll
        for (int tsub = 0; tsub < 2; ++tsub)
#pragma unroll
            for (int kh = 0; kh < 2; ++kh)
                aq[tsub][kh] = *(const bf16x8*)&QKf[buf][tsub * 2 + kh][lane][0];

#pragma unroll
        for (int st = 0; st < 4; ++st) {
            f32x4 c0 = {0.f, 0.f, 0.f, 0.f};
            f32x4 c1 = {0.f, 0.f, 0.f, 0.f};
            c0 = __builtin_amdgcn_mfma_f32_16x16x32_bf16(aq[0][0], bk[st][0], c0, 0, 0, 0);
            c1 = __builtin_amdgcn_mfma_f32_16x16x32_bf16(aq[1][0], bk[st][0], c1, 0, 0, 0);
            c0 = __builtin_amdgcn_mfma_f32_16x16x32_bf16(aq[0][1], bk[st][1], c0, 0, 0, 0);
            c1 = __builtin_amdgcn_mfma_f32_16x16x32_bf16(aq[1][1], bk[st][1], c1, 0, 0, 0);
            csum[st] += exp_pow16(c0[0]) + exp_pow16(c0[1])
                      + exp_pow16(c0[2]) + exp_pow16(c0[3])
                      + exp_pow16(c1[0]) + exp_pow16(c1[1])
                      + exp_pow16(c1[2]) + exp_pow16(c1[3]);
        }
        __builtin_amdgcn_s_waitcnt(0xc07f);   // lgkmcnt(0): my LDS reads done
        __builtin_amdgcn_s_barrier();         // buf safe to overwrite
        buf = nb;
    }

#pragma unroll
    for (int st = 0; st < 4; ++st) {
        float r = csum[st];
        r += __shfl_xor(r, 16, 64);
        r += __shfl_xor(r, 32, 64);
        if (quad == 0)
            Dpart[((size_t)z * BB + b) * TT + s0 + st * 16 + l15] = r;
    }
}

// ---- kernel 3: VsT[b][h][s] = bf16(Kb[b][s][h]) / sum_z Dpart[z][b][s] -----
__global__ __launch_bounds__(256) void vscale_kernel(
        const __bf16* __restrict__ Kb, const float* __restrict__ Dpart,
        __bf16* __restrict__ VsT) {
    __shared__ float tile[64][65];
    __shared__ float Rs[64];
    int b = blockIdx.y;
    int s0 = blockIdx.x * 64;
    int c = threadIdx.x & 63;
    int rr = threadIdx.x >> 6;
    if (threadIdx.x < 64) {
        size_t si = (size_t)b * TT + s0 + threadIdx.x;
        float d = Dpart[si];
#pragma unroll
        for (int zz = 1; zz < ZT; ++zz) d += Dpart[(size_t)zz * BB * TT + si];
        Rs[threadIdx.x] = 1.0f / d;
    }
    __syncthreads();
    const __bf16* Kbase = Kb + ((size_t)b * TT + s0) * HH;
#pragma unroll
    for (int i = rr; i < 64; i += 4)
        tile[i][c] = (float)Kbase[(size_t)i * HH + c] * Rs[i];
    __syncthreads();
    __bf16* Vb = VsT + (size_t)b * HH * TT;
#pragma unroll
    for (int i = rr; i < 64; i += 4)
        Vb[(size_t)i * TT + s0 + c] = (__bf16)tile[c][i];
}

// ---- kernel 4: OP[z][b][t][h] = sum_{s in slice z} exp(S_ts) * VsT[h][s] ---
// R11: E-direct PV. QK computes S^T (C: row=s=quad*4+r, col=t=l15). That C
// layout IS the B-frag layout of v_mfma_f32_16x16x16_bf16 (B[k=quad*4+j][n=l15])
// — so exp'd scores feed PV directly in registers: out^T[h,t] += V^T[h,s]E^T[s,t]
// with A = V^T frag (A[m=h=l15][k=s=quad*4+j]) read as b64 from the SAME PVf
// staging layout as R8 (slot lane*16 = VsT[16w+l15][s+quad*8..+7]).
// No E ds_write / lgkm drain / aE ds_read; Etile LDS gone (26.6 -> 16.4 KB).
__global__ __launch_bounds__(256, 4) void out_mfma(
        const __bf16* __restrict__ Qb, const __bf16* __restrict__ Kb,
        const __bf16* __restrict__ VsT, float* __restrict__ OP) {
    __shared__ __bf16 QKf[2][4][64][8];     // [buf][region sub*2+kh][lane][8]
    __shared__ __bf16 PVf[2][4][64][8];     // [buf][region ht][slot lane][8]

    int lane = threadIdx.x & 63;
    int w = threadIdx.x >> 6;
    int quad = lane >> 4;
    int l15 = lane & 15;
    int b = blockIdx.y;
    int z = blockIdx.z;
    int t0 = blockIdx.x * 128 + w * 32;

    const __bf16* Qbb = Qb + (size_t)b * TT * HH;
    const __bf16* Kbb = Kb + (size_t)b * TT * HH;
    const __bf16* Vbb = VsT + (size_t)b * HH * TT;

    bf16x8 aq[2][2];
#pragma unroll
    for (int tile = 0; tile < 2; ++tile) {
        const __bf16* qrow = Qbb + (size_t)(t0 + tile * 16 + l15) * HH + quad * 8;
        aq[tile][0] = *(const bf16x8*)(qrow);
        aq[tile][1] = *(const bf16x8*)(qrow + 32);
    }

    f32x4 acc[2][4];    // out^T tiles: row h_local=quad*4+r (+16ht), col t=l15
#pragma unroll
    for (int tile = 0; tile < 2; ++tile)
#pragma unroll
        for (int ht = 0; ht < 4; ++ht)
            acc[tile][ht] = (f32x4){0.f, 0.f, 0.f, 0.f};

    const __bf16* gA = Kbb + (size_t)((w >> 1) * 16 + l15) * HH + quad * 8 + (w & 1) * 32;
    const __bf16* gB = Vbb + (size_t)(w * 16 + l15) * TT + quad * 8;

    const int SL = TT / gridDim.z;
    int s0z = z * SL, send = s0z + SL;

    __builtin_amdgcn_global_load_lds((gl_void*)(gA + (size_t)s0z * HH),
                                     (lds_void*)&QKf[0][w][0][0], 16, 0, 0);
    __builtin_amdgcn_global_load_lds((gl_void*)(gB + s0z),
                                     (lds_void*)&PVf[0][w][0][0], 16, 0, 0);

    int buf = 0;
    for (int s = s0z; s < send; s += 32) {
        int snext = (s + 32 < send) ? (s + 32) : s0z;   // last iter: dummy reload
        int nb = buf ^ 1;
        __builtin_amdgcn_global_load_lds((gl_void*)(gA + (size_t)snext * HH),
                                         (lds_void*)&QKf[nb][w][0][0], 16, 0, 0);
        __builtin_amdgcn_global_load_lds((gl_void*)(gB + snext),
                                         (lds_void*)&PVf[nb][w][0][0], 16, 0, 0);
        __builtin_amdgcn_s_waitcnt(0x0f72);   // vmcnt(2): chunk-s stages done
        __builtin_amdgcn_s_barrier();

        bf16x8 bk[2][2];
#pragma unroll
        for (int sub = 0; sub < 2; ++sub)
#pragma unroll
            for (int kh = 0; kh < 2; ++kh)
                bk[sub][kh] = *(const bf16x8*)&QKf[buf][sub * 2 + kh][lane][0];

        // V^T A-frags: va[ht][sub] = A[m=l15][k=sub*16+quad*4+j] — b64 from
        // PVf region ht at elem offset ((2*sub+(quad>>1))*16 + l15)*8 + (quad&1)*4
        bf16x4 va[4][2];
#pragma unroll
        for (int ht = 0; ht < 4; ++ht)
#pragma unroll
            for (int sub = 0; sub < 2; ++sub)
                va[ht][sub] = *(const bf16x4*)(&PVf[buf][ht][0][0]
                    + ((2 * sub + (quad >> 1)) * 16 + l15) * 8 + (quad & 1) * 4);

#pragma unroll
        for (int tile = 0; tile < 2; ++tile) {
#pragma unroll
            for (int sub = 0; sub < 2; ++sub) {
                // S^T: C[s=quad*4+r][t=l15]
                f32x4 c = {0.f, 0.f, 0.f, 0.f};
                c = __builtin_amdgcn_mfma_f32_16x16x32_bf16(bk[sub][0], aq[tile][0], c, 0, 0, 0);
                c = __builtin_amdgcn_mfma_f32_16x16x32_bf16(bk[sub][1], aq[tile][1], c, 0, 0, 0);
                bf16x4 eT;
#pragma unroll
                for (int r = 0; r < 4; ++r)
                    eT[r] = (__bf16)exp_pow16(c[r]);
                // eT IS the K=16 B-frag of E^T — PV directly, no LDS round-trip
#pragma unroll
                for (int ht = 0; ht < 4; ++ht)
                    acc[tile][ht] = mfma16_bf16(va[ht][sub], eT, acc[tile][ht]);
            }
        }
        __builtin_amdgcn_s_waitcnt(0xc07f);   // my LDS reads complete
        __builtin_amdgcn_s_barrier();         // buf safe to overwrite
        buf = nb;
    }

    // Epilogue: acc[tile][ht] row h=16ht+quad*4+r, col t=l15 -> OP[t][h],
    // 4 consecutive h per lane = one dwordx4 store each.
    float* op = OP + (((size_t)z * BB + b) * TT + t0) * HH;
#pragma unroll
    for (int tile = 0; tile < 2; ++tile) {
#pragma unroll
        for (int ht = 0; ht < 4; ++ht) {
            f32x4 v = acc[tile][ht];
            *(f32x4*)&op[(size_t)(tile * 16 + l15) * HH + 16 * ht + quad * 4] = v;
        }
    }
}

// ---- kernel 5: out = sum_z OP[z] -------------------------------------------
__global__ __launch_bounds__(256) void reduce_kernel(
        const float* __restrict__ OP, float* __restrict__ out, int nslice) {
    size_t i = (size_t)blockIdx.x * 256 + threadIdx.x;   // float4 units
    const size_t N4 = (size_t)BB * TT * HH / 4;
    if (i >= N4) return;
    const float4* p = (const float4*)OP;
    float4 a = p[i];
    for (int zz = 1; zz < nslice; ++zz) {
        float4 v = p[(size_t)zz * N4 + i];
        a.x += v.x; a.y += v.y; a.z += v.z; a.w += v.w;
    }
    ((float4*)out)[i] = a;
}

extern "C" void kernel_launch(void* const* d_in, const int* in_sizes, int n_in,
                              void* d_out, int out_size, void* d_ws, size_t ws_size,
                              hipStream_t stream) {
    const float* x  = (const float*)d_in[0];
    const float* Wq = (const float*)d_in[1];
    const float* Wk = (const float*)d_in[2];
    // d_in[3] (Wv) unused: reference computes v = x @ Wk (faithful quirk).

    const size_t NE = (size_t)BB * TT * HH;     // 2,097,152
    size_t base = NE * 2 * 3 + (size_t)ZT * BB * TT * 4;
    int nslice = 4;
    if (base + (size_t)4 * NE * 4 > ws_size) nslice = 2;

    char* wp = (char*)d_ws;
    __bf16* Qb    = (__bf16*)wp;  wp += NE * 2;
    __bf16* Kb    = (__bf16*)wp;  wp += NE * 2;
    __bf16* VsT   = (__bf16*)wp;  wp += NE * 2;
    float*  Dpart = (float*)wp;   wp += (size_t)ZT * BB * TT * 4;
    float*  OP    = (float*)wp;
    float* out = (float*)d_out;

    proj_kernel<<<BB * TT / 4, 256, 0, stream>>>(x, Wq, Wk, Qb, Kb);
    colsum_mfma<<<dim3(TT / 256, BB, ZT), 256, 0, stream>>>(Qb, Kb, Dpart);
    vscale_kernel<<<dim3(TT / 64, BB), 256, 0, stream>>>(Kb, Dpart, VsT);
    out_mfma<<<dim3(TT / 128, BB, nslice), 256, 0, stream>>>(Qb, Kb, VsT, OP);
    reduce_kernel<<<(int)((NE / 4 + 255) / 256), 256, 0, stream>>>(OP, out, nslice);
}